// Round 1
// baseline (1776.936 us; speedup 1.0000x reference)
//
#include <hip/hip_runtime.h>

#define NN 16384

typedef __attribute__((ext_vector_type(4))) float vf4;
typedef __attribute__((ext_vector_type(8))) short vbf8;
typedef __attribute__((ext_vector_type(4))) short vs4;

static __device__ __forceinline__ unsigned short f2bf(float f) {
  union { float f; unsigned u; } x; x.f = f;
  unsigned r = x.u + 0x7FFFu + ((x.u >> 16) & 1u);
  return (unsigned short)(r >> 16);
}
static __device__ __forceinline__ float bf2f(unsigned short b) {
  union { unsigned u; float f; } x; x.u = ((unsigned)b) << 16;
  return x.f;
}

// ---------------------------------------------------------------------------
// k_xw1: Vt1[n][row] = bf16( (X @ W1)[row][n] )   (transposed output)
// ---------------------------------------------------------------------------
__global__ __launch_bounds__(256) void k_xw1(const float* __restrict__ X,
                                             const float* __restrict__ W1,
                                             unsigned short* __restrict__ Vt) {
  __shared__ float W1s[128 * 64];
  const int tid = threadIdx.x;
  for (int i = tid; i < 128 * 64; i += 256) W1s[i] = W1[i];
  __syncthreads();
  const int n = tid & 63;
  const long row = (long)blockIdx.x * 4 + (tid >> 6);
  const float* xr = X + row * 128;
  float acc = 0.f;
#pragma unroll
  for (int f = 0; f < 128; f += 4) {
    vf4 xv = *(const vf4*)(xr + f);
    acc += xv.x * W1s[f * 64 + n] + xv.y * W1s[(f + 1) * 64 + n] +
           xv.z * W1s[(f + 2) * 64 + n] + xv.w * W1s[(f + 3) * 64 + n];
  }
  Vt[(long)n * NN + row] = f2bf(acc);
}

// ---------------------------------------------------------------------------
// kA: H[row][n] = bf16( sigmoid( sum_k A[row][k] * Vt[n][k] + bias[n] ) )
// A fp32 [NN][NN], Vt bf16 [64][NN] (k-contiguous). Memory-bound on A stream.
// Block: 256 thr / 4 waves, 32 rows x 64 cols, KC=64, 256 K-iterations.
// ---------------------------------------------------------------------------
__global__ __launch_bounds__(256, 2) void kA(const float* __restrict__ A,
                                             const unsigned short* __restrict__ Vt,
                                             const float* __restrict__ bias,
                                             unsigned short* __restrict__ H) {
  __shared__ unsigned short Als[32][72];  // +8 pad: 144B rows -> <=2-way banks
  __shared__ unsigned short Vls[64][72];

  const int tid = threadIdx.x;
  const int lane = tid & 63;
  const int wave = tid >> 6;
  const long R0 = (long)blockIdx.x * 32;

  // A staging: 16 threads per row * float4; rows (tid>>4) and +16
  const int ar = tid >> 4;
  const int ac = (tid & 15) * 4;
  const float* aP0 = A + (R0 + ar) * (long)NN + ac;
  const float* aP1 = A + (R0 + ar + 16) * (long)NN + ac;

  // V staging: 8 threads per n-row * 16B; rows (tid>>3) and +32
  const int vn = tid >> 3;
  const int vk = (tid & 7) * 8;
  const unsigned short* vP0 = Vt + (long)vn * NN + vk;
  const unsigned short* vP1 = Vt + (long)(vn + 32) * NN + vk;

  // wave tile: 16 rows (mo) x 32 cols (no, two 16-col ntiles)
  const int mo = (wave & 1) * 16;
  const int no = (wave >> 1) * 32;
  const int fr = lane & 15;
  const int fk = (lane >> 4) * 8;

  vf4 acc0 = {0.f, 0.f, 0.f, 0.f};
  vf4 acc1 = {0.f, 0.f, 0.f, 0.f};

  vf4 a0 = *(const vf4*)aP0;
  vf4 a1 = *(const vf4*)aP1;
  vf4 v0 = *(const vf4*)vP0;
  vf4 v1 = *(const vf4*)vP1;

  for (int it = 0; it < 256; ++it) {
    const int nx = (it < 255) ? (it + 1) * 64 : 255 * 64;
    // issue next chunk's loads before consuming current -> stays in flight
    vf4 na0 = *(const vf4*)(aP0 + nx);
    vf4 na1 = *(const vf4*)(aP1 + nx);
    vf4 nv0 = *(const vf4*)(vP0 + nx);
    vf4 nv1 = *(const vf4*)(vP1 + nx);

    vs4 pa, pb;
    pa.x = (short)f2bf(a0.x); pa.y = (short)f2bf(a0.y);
    pa.z = (short)f2bf(a0.z); pa.w = (short)f2bf(a0.w);
    pb.x = (short)f2bf(a1.x); pb.y = (short)f2bf(a1.y);
    pb.z = (short)f2bf(a1.z); pb.w = (short)f2bf(a1.w);
    *(vs4*)&Als[ar][ac] = pa;
    *(vs4*)&Als[ar + 16][ac] = pb;
    *(vf4*)&Vls[vn][vk] = v0;        // raw bf16 bits, 16B
    *(vf4*)&Vls[vn + 32][vk] = v1;
    __syncthreads();

    const unsigned short* ap = &Als[mo + fr][fk];
    const unsigned short* bp0 = &Vls[no + fr][fk];
    const unsigned short* bp1 = &Vls[no + 16 + fr][fk];
    vbf8 af0 = *(const vbf8*)ap;
    vbf8 b00 = *(const vbf8*)bp0;
    vbf8 b10 = *(const vbf8*)bp1;
    acc0 = __builtin_amdgcn_mfma_f32_16x16x32_bf16(af0, b00, acc0, 0, 0, 0);
    acc1 = __builtin_amdgcn_mfma_f32_16x16x32_bf16(af0, b10, acc1, 0, 0, 0);
    vbf8 af1 = *(const vbf8*)(ap + 32);
    vbf8 b01 = *(const vbf8*)(bp0 + 32);
    vbf8 b11 = *(const vbf8*)(bp1 + 32);
    acc0 = __builtin_amdgcn_mfma_f32_16x16x32_bf16(af1, b01, acc0, 0, 0, 0);
    acc1 = __builtin_amdgcn_mfma_f32_16x16x32_bf16(af1, b11, acc1, 0, 0, 0);
    __syncthreads();

    a0 = na0; a1 = na1; v0 = nv0; v1 = nv1;
  }

  // C/D layout: col = lane&15, row = (lane>>4)*4 + reg   [m89-verified]
  const int orow = (lane >> 4) * 4;
  const int ocol = lane & 15;
#pragma unroll
  for (int r = 0; r < 4; ++r) {
    const long gr = R0 + mo + orow + r;
    const int c0 = no + ocol;
    const float x0 = acc0[r] + bias[c0];
    H[gr * 64 + c0] = f2bf(1.f / (1.f + __expf(-x0)));
    const int c1 = no + 16 + ocol;
    const float x1 = acc1[r] + bias[c1];
    H[gr * 64 + c1] = f2bf(1.f / (1.f + __expf(-x1)));
  }
}

// ---------------------------------------------------------------------------
// k_hw2: Vt2[n][row] = bf16( (h1 @ W2)[row][n] )  (transposed output)
// ---------------------------------------------------------------------------
__global__ __launch_bounds__(256) void k_hw2(const unsigned short* __restrict__ h1,
                                             const float* __restrict__ W2,
                                             unsigned short* __restrict__ Vt2) {
  __shared__ float W2s[64 * 64];
  const int tid = threadIdx.x;
  for (int i = tid; i < 64 * 64; i += 256) W2s[i] = W2[i];
  __syncthreads();
  const int n = tid & 63;
  const long row = (long)blockIdx.x * 4 + (tid >> 6);
  const unsigned short* hr = h1 + row * 64;
  float acc = 0.f;
#pragma unroll
  for (int m = 0; m < 64; m += 4) {
    vs4 hh = *(const vs4*)(hr + m);
    acc += bf2f((unsigned short)hh.x) * W2s[m * 64 + n] +
           bf2f((unsigned short)hh.y) * W2s[(m + 1) * 64 + n] +
           bf2f((unsigned short)hh.z) * W2s[(m + 2) * 64 + n] +
           bf2f((unsigned short)hh.w) * W2s[(m + 3) * 64 + n];
  }
  Vt2[(long)n * NN + row] = f2bf(acc);
}

// ---------------------------------------------------------------------------
// k_pcat: P[node][u]     = bf16( sum_m h2[node][m] * Wd[m][u] )      (u<256)
//         P[node][256+u] = bf16( sum_m h2[node][m] * Wd[64+m][u] )
// Block: 16 nodes, thread u = tid, 32 fp32 accumulators.
// ---------------------------------------------------------------------------
__global__ __launch_bounds__(256, 2) void k_pcat(const unsigned short* __restrict__ h2,
                                                 const float* __restrict__ Wd,
                                                 unsigned short* __restrict__ P) {
  __shared__ unsigned short Wds[64 * 256];  // one 64-row half at a time (32 KiB)
  __shared__ float h2t[64 * 16];            // transposed: [m][r]
  const int tid = threadIdx.x;
  const long R0 = (long)blockIdx.x * 16;
  for (int i = tid; i < 1024; i += 256) {
    const int r = i >> 6, m = i & 63;
    h2t[m * 16 + r] = bf2f(h2[(R0 + r) * 64 + m]);
  }
  float acc[32];
#pragma unroll
  for (int r = 0; r < 32; ++r) acc[r] = 0.f;
  const int u = tid;
#pragma unroll
  for (int half = 0; half < 2; ++half) {
    __syncthreads();  // protect Wds reuse (and h2t on first pass)
    for (int i = tid; i < 4096; i += 256) {
      vf4 w = *(const vf4*)(Wd + half * 16384 + i * 4);
      vs4 p;
      p.x = (short)f2bf(w.x); p.y = (short)f2bf(w.y);
      p.z = (short)f2bf(w.z); p.w = (short)f2bf(w.w);
      *(vs4*)&Wds[i * 4] = p;
    }
    __syncthreads();
#pragma unroll 4
    for (int m = 0; m < 64; ++m) {
      const float wv = bf2f(Wds[m * 256 + u]);
      const vf4 h0 = *(const vf4*)&h2t[m * 16 + 0];
      const vf4 h1v = *(const vf4*)&h2t[m * 16 + 4];
      const vf4 h2v = *(const vf4*)&h2t[m * 16 + 8];
      const vf4 h3 = *(const vf4*)&h2t[m * 16 + 12];
      acc[0 + half] += h0.x * wv;  acc[2 + half] += h0.y * wv;
      acc[4 + half] += h0.z * wv;  acc[6 + half] += h0.w * wv;
      acc[8 + half] += h1v.x * wv; acc[10 + half] += h1v.y * wv;
      acc[12 + half] += h1v.z * wv; acc[14 + half] += h1v.w * wv;
      acc[16 + half] += h2v.x * wv; acc[18 + half] += h2v.y * wv;
      acc[20 + half] += h2v.z * wv; acc[22 + half] += h2v.w * wv;
      acc[24 + half] += h3.x * wv;  acc[26 + half] += h3.y * wv;
      acc[28 + half] += h3.z * wv;  acc[30 + half] += h3.w * wv;
    }
  }
#pragma unroll
  for (int r = 0; r < 16; ++r) {
    P[(R0 + r) * 512 + u] = f2bf(acc[2 * r]);
    P[(R0 + r) * 512 + 256 + u] = f2bf(acc[2 * r + 1]);
  }
}

// ---------------------------------------------------------------------------
// k_edge: one wave per edge (4 edges looped). d = relu(P1[src]+P2[dst]+bd),
// logits = d@Wo + bo, softmax, * mask. Lane handles u = lane*4..lane*4+3.
// ---------------------------------------------------------------------------
__global__ __launch_bounds__(256) void k_edge(const int* __restrict__ edges,
                                              const int* __restrict__ mask,
                                              const unsigned short* __restrict__ P,
                                              const float* __restrict__ bd,
                                              const float* __restrict__ Wo,
                                              const float* __restrict__ bo,
                                              float* __restrict__ out) {
  const int tid = threadIdx.x;
  const int lane = tid & 63;
  const int wave = tid >> 6;
  const int u0 = lane * 4;
  const vf4 bdv = *(const vf4*)(bd + u0);
  const vf4 woA = *(const vf4*)(Wo + u0 * 2);      // Wo[u0][0..1], Wo[u0+1][0..1]
  const vf4 woB = *(const vf4*)(Wo + u0 * 2 + 4);  // Wo[u0+2][0..1], Wo[u0+3][0..1]
  const float bo0 = bo[0], bo1 = bo[1];
  const long ebase = ((long)blockIdx.x * 4 + wave) * 4;
#pragma unroll
  for (int j = 0; j < 4; ++j) {
    const long e = ebase + j;
    const int src = edges[2 * e];
    const int dst = edges[2 * e + 1];
    const vs4 q1 = *(const vs4*)(P + (long)src * 512 + u0);
    const vs4 q2 = *(const vs4*)(P + (long)dst * 512 + 256 + u0);
    const float d0 = fmaxf(bf2f((unsigned short)q1.x) + bf2f((unsigned short)q2.x) + bdv.x, 0.f);
    const float d1 = fmaxf(bf2f((unsigned short)q1.y) + bf2f((unsigned short)q2.y) + bdv.y, 0.f);
    const float d2 = fmaxf(bf2f((unsigned short)q1.z) + bf2f((unsigned short)q2.z) + bdv.z, 0.f);
    const float d3 = fmaxf(bf2f((unsigned short)q1.w) + bf2f((unsigned short)q2.w) + bdv.w, 0.f);
    float a0 = d0 * woA.x + d1 * woA.z + d2 * woB.x + d3 * woB.z;
    float a1 = d0 * woA.y + d1 * woA.w + d2 * woB.y + d3 * woB.w;
#pragma unroll
    for (int s = 32; s; s >>= 1) {
      a0 += __shfl_xor(a0, s);
      a1 += __shfl_xor(a1, s);
    }
    if (lane == 0) {
      const float l0 = a0 + bo0, l1 = a1 + bo1;
      const float mx = fmaxf(l0, l1);
      const float e0 = __expf(l0 - mx), e1 = __expf(l1 - mx);
      const float inv = 1.f / (e0 + e1);
      const float mk = (float)mask[e];
      out[2 * e] = e0 * inv * mk;
      out[2 * e + 1] = e1 * inv * mk;
    }
  }
}

// ---------------------------------------------------------------------------
extern "C" void kernel_launch(void* const* d_in, const int* in_sizes, int n_in,
                              void* d_out, int out_size, void* d_ws, size_t ws_size,
                              hipStream_t stream) {
  const float* X = (const float*)d_in[0];
  const float* A = (const float*)d_in[1];
  const int* edges = (const int*)d_in[2];
  const int* mask = (const int*)d_in[3];
  const float* W1 = (const float*)d_in[4];
  const float* b1 = (const float*)d_in[5];
  const float* W2 = (const float*)d_in[6];
  const float* b2 = (const float*)d_in[7];
  const float* Wd = (const float*)d_in[8];
  const float* bd = (const float*)d_in[9];
  const float* Wo = (const float*)d_in[10];
  const float* bo = (const float*)d_in[11];
  float* out = (float*)d_out;

  unsigned short* Vt1 = (unsigned short*)d_ws;   // [64][NN] bf16, 2 MiB
  unsigned short* Vt2 = Vt1 + (size_t)64 * NN;   // [64][NN] bf16, 2 MiB
  unsigned short* h1 = Vt2 + (size_t)64 * NN;    // [NN][64] bf16, 2 MiB
  unsigned short* h2 = h1 + (size_t)NN * 64;     // [NN][64] bf16, 2 MiB
  unsigned short* P = h2 + (size_t)NN * 64;      // [NN][512] bf16, 16 MiB

  k_xw1<<<NN / 4, 256, 0, stream>>>(X, W1, Vt1);
  kA<<<NN / 32, 256, 0, stream>>>(A, Vt1, b1, h1);
  k_hw2<<<NN / 4, 256, 0, stream>>>(h1, W2, Vt2);
  kA<<<NN / 32, 256, 0, stream>>>(A, Vt2, b2, h2);
  k_pcat<<<NN / 16, 256, 0, stream>>>(h2, Wd, P);
  k_edge<<<524288 / 16, 256, 0, stream>>>(edges, mask, P, bd, Wo, bo, out);
}